// Round 2
// baseline (3047.987 us; speedup 1.0000x reference)
//
#include <hip/hip_runtime.h>

typedef _Float16 f16;
typedef __attribute__((ext_vector_type(4))) _Float16 f16x4;
typedef __attribute__((ext_vector_type(8))) _Float16 f16x8;
typedef __attribute__((ext_vector_type(4))) float f32x4;

#define NB   512
#define NI   128
#define NH   1024
#define NG   4096
#define NSEQ 96

__device__ __forceinline__ float sigm(float x)  { return 1.0f / (1.0f + __expf(-x)); }
__device__ __forceinline__ float tanhf_(float x){ return 2.0f / (1.0f + __expf(-2.0f * x)) - 1.0f; }

// R12: persistent kernel with a HAND-ROLLED grid barrier (no cooperative
// groups). R11 failed (absmax 0.28 ~ full y-scale) with compute verified
// identical to passing R10 -> the coop launch / grid.sync under graph
// capture is the suspect. Barrier: monotonic counter in workspace;
// per step, thread 0: threadfence (agent release) -> atomicAdd -> spin
// __hip_atomic_load >= t*256 -> threadfence (agent acquire) -> syncthreads.
// 256 blocks x 128KiB LDS = exactly 1 block/CU (co-resident by construction).
// Bounded spin: on timeout set a flag and stop waiting (fail fast, no hang).

__global__ __launch_bounds__(256)
void prep1_kernel(const float* __restrict__ xt, const float* __restrict__ hidden,
                  const float* __restrict__ W_ih, const float* __restrict__ b_ih,
                  const float* __restrict__ b_hh, const float* __restrict__ b_fc,
                  f16* __restrict__ wih, f16* __restrict__ xbuf,
                  f16* __restrict__ h0, float* __restrict__ bias_eff,
                  float* __restrict__ out, unsigned* __restrict__ bar)
{
    const int gid = blockIdx.x * 256 + threadIdx.x;
    const int GSZ = 256 * 256;
    if (gid == 0) *bar = 0u;              // grid-barrier counter (re-zeroed every launch)
    { const float4* s = (const float4*)W_ih; f16x4* d = (f16x4*)wih;
      for (int i = gid; i < NG * NI / 4; i += GSZ) { float4 v = s[i]; d[i] = f16x4{(f16)v.x,(f16)v.y,(f16)v.z,(f16)v.w}; } }
    { const float4* s = (const float4*)xt; f16x4* d = (f16x4*)xbuf;
      for (int i = gid; i < NB * NI / 4; i += GSZ) { float4 v = s[i]; d[i] = f16x4{(f16)v.x,(f16)v.y,(f16)v.z,(f16)v.w}; } }
    { const float4* s = (const float4*)hidden; f16x4* d = (f16x4*)h0;
      for (int i = gid; i < NB * NH / 4; i += GSZ) { float4 v = s[i]; d[i] = f16x4{(f16)v.x,(f16)v.y,(f16)v.z,(f16)v.w}; } }
    if (gid < NB * NSEQ) out[gid] = b_fc[NI - 1];   // atomic-accumulation base for cols 1..95
    if (gid < NG) {                       // bias_eff[n] = b_ih+b_hh + W_ih[n,:].b_fc
        float s = b_ih[gid] + b_hh[gid];
        const float* wr = W_ih + gid * NI;
        for (int j = 0; j < NI; ++j) s += wr[j] * b_fc[j];
        bias_eff[gid] = s;
    }
}

// W_eff = W_hh + W_ih @ W_fc  -> fp16.  512 blocks: (nt=bid>>3)x(kt=bid&7),
// tile = 64 gate-rows x 128 k-cols, K=128.
__global__ __launch_bounds__(256)
void prep2_kernel(const f16* __restrict__ wih, const float* __restrict__ W_fc,
                  const float* __restrict__ W_hh, f16* __restrict__ weff)
{
    __shared__ f16 ldsW[64 * 136];        // A tile 64x128 fp16, pitch 136

    const int tid = threadIdx.x;
    const int nt = blockIdx.x >> 3, kt = blockIdx.x & 7;
    const int w = tid >> 6, lane = tid & 63, quad = lane >> 4, l16 = lane & 15;

    for (int s = 0; s < 4; ++s) {
        const int slot = tid + s * 256;            // 1024 vec8 slots
        const int row = slot >> 4, colv = slot & 15;
        *(f16x8*)(ldsW + row * 136 + colv * 8) =
            *(const f16x8*)(wih + (nt * 64 + row) * NI + colv * 8);
    }
    __syncthreads();

    f32x4 acc[4][2];
#pragma unroll
    for (int mt = 0; mt < 4; ++mt) { acc[mt][0] = f32x4{0,0,0,0}; acc[mt][1] = f32x4{0,0,0,0}; }

    const int nc0 = kt * 128 + w * 32;
#pragma unroll
    for (int c = 0; c < 4; ++c) {
        f16x8 bf0, bf1;
#pragma unroll
        for (int j = 0; j < 8; ++j) {
            const int krow = c * 32 + quad * 8 + j;
            bf0[j] = (f16)W_fc[krow * NH + nc0 + l16];
            bf1[j] = (f16)W_fc[krow * NH + nc0 + 16 + l16];
        }
#pragma unroll
        for (int mt = 0; mt < 4; ++mt) {
            f16x8 afr = *(const f16x8*)(ldsW + (mt * 16 + l16) * 136 + c * 32 + quad * 8);
            acc[mt][0] = __builtin_amdgcn_mfma_f32_16x16x32_f16(afr, bf0, acc[mt][0], 0, 0, 0);
            acc[mt][1] = __builtin_amdgcn_mfma_f32_16x16x32_f16(afr, bf1, acc[mt][1], 0, 0, 0);
        }
    }

#pragma unroll
    for (int mt = 0; mt < 4; ++mt)
#pragma unroll
        for (int r = 0; r < 4; ++r) {
            const int n = nt * 64 + mt * 16 + quad * 4 + r;
            weff[n * NH + nc0 + l16]      = (f16)(acc[mt][0][r] + W_hh[n * NH + nc0 + l16]);
            weff[n * NH + nc0 + 16 + l16] = (f16)(acc[mt][1][r] + W_hh[n * NH + nc0 + 16 + l16]);
        }
}

// t=0: gates = x0@W_ih^T + h0@W_hh^T + (b_ih+b_hh); K=1152. W_hh read f32.
__global__ __launch_bounds__(256)
void step0_kernel(const f16* __restrict__ xbuf, const f16* __restrict__ hin,
                  f16* __restrict__ hout, const f16* __restrict__ wih,
                  const float* __restrict__ W_hh, const float* __restrict__ b_ih,
                  const float* __restrict__ b_hh, float* __restrict__ cglob)
{
    __shared__ f16   ldsA[2 * 64 * 40];
    __shared__ float gbuf[4][64][33];

    const int tid = threadIdx.x, bid = blockIdx.x;
    const int r0 = (bid >> 5) * 64, u0 = (bid & 31) * 32;
    const int w = tid >> 6, lane = tid & 63, quad = lane >> 4, l16 = lane & 15;
    const int srow = tid >> 2, skk = (tid & 3) * 8;

    const int n0g = w * NH + u0 + l16;
    const f16*   wip0 = wih + n0g * NI + quad * 8;
    const f16*   wip1 = wip0 + 16 * NI;
    const float* whf0 = W_hh + n0g * NH + quad * 8;
    const float* whf1 = whf0 + 16 * NH;
    const float bias0 = b_ih[n0g]      + b_hh[n0g];
    const float bias1 = b_ih[n0g + 16] + b_hh[n0g + 16];

    const f16* xrow = xbuf + (r0 + srow) * NI + skk;
    const f16* hrow = hin  + (r0 + srow) * NH + skk;

    f32x4 acc[4][2];
#pragma unroll
    for (int mt = 0; mt < 4; ++mt) { acc[mt][0] = f32x4{0,0,0,0}; acc[mt][1] = f32x4{0,0,0,0}; }

    auto loadA = [&](int kb) -> f16x8 {
        const int k0 = kb * 32;
        if (k0 < NI) return *(const f16x8*)(xrow + k0);
        return *(const f16x8*)(hrow + (k0 - NI));
    };
    auto cvt8 = [&](const float* p) -> f16x8 {
        float4 a = *(const float4*)p, b = *(const float4*)(p + 4);
        return f16x8{(f16)a.x,(f16)a.y,(f16)a.z,(f16)a.w,(f16)b.x,(f16)b.y,(f16)b.z,(f16)b.w};
    };
    auto loadB0 = [&](int kb) -> f16x8 {
        const int k0 = kb * 32;
        if (k0 < NI) return *(const f16x8*)(wip0 + k0);
        return cvt8(whf0 + (k0 - NI));
    };
    auto loadB1 = [&](int kb) -> f16x8 {
        const int k0 = kb * 32;
        if (k0 < NI) return *(const f16x8*)(wip1 + k0);
        return cvt8(whf1 + (k0 - NI));
    };

    f16x8 av = loadA(0);
    *(f16x8*)(ldsA + srow * 40 + skk) = av;
    av = loadA(1);
    f16x8 b0 = loadB0(0), b1 = loadB1(0);

    for (int kb = 0; kb < 36; ++kb) {
        __syncthreads();
        if (kb + 1 < 36) {
            *(f16x8*)(ldsA + ((kb + 1) & 1) * 2560 + srow * 40 + skk) = av;
            av = loadA(kb + 2 < 36 ? kb + 2 : 35);
        }
        const int kn = (kb + 1 < 36) ? kb + 1 : 35;
        f16x8 nb0 = loadB0(kn), nb1 = loadB1(kn);
        const f16* abase = ldsA + (kb & 1) * 2560 + l16 * 40 + quad * 8;
#pragma unroll
        for (int mt = 0; mt < 4; ++mt) {
            f16x8 afr = *(const f16x8*)(abase + mt * 640);
            acc[mt][0] = __builtin_amdgcn_mfma_f32_16x16x32_f16(afr, b0, acc[mt][0], 0, 0, 0);
            acc[mt][1] = __builtin_amdgcn_mfma_f32_16x16x32_f16(afr, b1, acc[mt][1], 0, 0, 0);
        }
        b0 = nb0; b1 = nb1;
    }

#pragma unroll
    for (int mt = 0; mt < 4; ++mt)
#pragma unroll
        for (int r = 0; r < 4; ++r) {
            gbuf[w][mt * 16 + quad * 4 + r][l16]      = acc[mt][0][r] + bias0;
            gbuf[w][mt * 16 + quad * 4 + r][16 + l16] = acc[mt][1][r] + bias1;
        }
    __syncthreads();

    {
        const int uu = tid & 31, rbase = (tid >> 5) * 8;
#pragma unroll
        for (int s = 0; s < 8; ++s) {
            const int rr = rbase + s;
            const int gi = (r0 + rr) * NH + u0 + uu;
            const float iv = gbuf[0][rr][uu], fv = gbuf[1][rr][uu];
            const float gv = gbuf[2][rr][uu], ov = gbuf[3][rr][uu];
            const float cn = sigm(fv) * cglob[gi] + sigm(iv) * tanhf_(gv);
            cglob[gi] = cn;
            hout[gi]  = (f16)(sigm(ov) * tanhf_(cn));
        }
    }
}

// out[:,col] = h . W_fc[127,:] + b_fc[127]   (used for col 0 from h_1)
__global__ __launch_bounds__(256)
void colget_kernel(const f16* __restrict__ h, const float* __restrict__ wfc_last,
                   const float* __restrict__ b_fc, float* __restrict__ out, int col)
{
    __shared__ float dred[64][4];
    const int tid = threadIdx.x;
    const int row = blockIdx.x * 64 + (tid >> 2);
    const int q = tid & 3;
    const f16* hr = h + row * NH + q * 256;
    const float* wf = wfc_last + q * 256;
    float s = 0.f;
    for (int j = 0; j < 256; ++j) s += (float)hr[j] * wf[j];
    dred[tid >> 2][q] = s;
    __syncthreads();
    if (tid < 64)
        out[(blockIdx.x * 64 + tid) * NSEQ + col] =
            dred[tid][0] + dred[tid][1] + dred[tid][2] + dred[tid][3] + b_fc[127];
}

// Persistent kernel: steps t=1..95.  256 blocks (1/CU) x 256 threads.
// block = (rt = bid>>6: 128-row tile) x (us = bid&63: 16-unit strip).
// LDS: W_eff strip (64 gate-rows x 1024 K) in MFMA B-fragment order, 128 KiB.
// Wave w owns rows rt*128 + w*32 .. +31 and ALL 4 gates -> elementwise is
// lane-local.  Manual grid barrier between steps (monotonic counter).
__global__ __launch_bounds__(256, 1)
void lstm_persist(f16* h0, f16* h1,
                  const f16* __restrict__ weff, const float* __restrict__ bias_eff,
                  float* __restrict__ cglob, const float* __restrict__ wfc_last,
                  float* __restrict__ out, unsigned* __restrict__ bar)
{
    __shared__ f16 ldsB[4 * 32 * 64 * 8];   // 128 KiB: frag[(g*32+kb)*64 + lane]

    const int tid = threadIdx.x, bid = blockIdx.x;
    const int rt = bid >> 6, us = bid & 63;
    const int u0 = us * 16;
    const int w = tid >> 6, lane = tid & 63, quad = lane >> 4, l16 = lane & 15;

    // ---- preload W strip into LDS in fragment order (wave w owns gate g=w) ----
    {
        const f16* src = weff + (w * NH + u0 + l16) * NH + quad * 8;
        f16x8* dst = ((f16x8*)ldsB) + (w * 32) * 64 + lane;
#pragma unroll
        for (int kb = 0; kb < 32; ++kb)
            dst[kb * 64] = *(const f16x8*)(src + kb * 32);
    }

    const float bi = bias_eff[0 * NH + u0 + l16];
    const float bf = bias_eff[1 * NH + u0 + l16];
    const float bg = bias_eff[2 * NH + u0 + l16];
    const float bo = bias_eff[3 * NH + u0 + l16];
    const float wfc_u = wfc_last[u0 + l16];

    const int rows0 = rt * 128 + w * 32;
    const int aoff0 = (rows0 + l16) * NH + quad * 8;        // A-frag row tile 0
    const int aoff1 = (rows0 + 16 + l16) * NH + quad * 8;   // A-frag row tile 1
    const int gbase = (rows0 + quad * 4) * NH + u0 + l16;   // + (i*16 + r)*NH

    const f16x8* lb = (const f16x8*)ldsB;

    int dead = 0;                       // barrier-timeout flag (thread 0 only)
    __syncthreads();                    // W strip ready

#pragma unroll 1
    for (int t = 1; t < NSEQ; ++t) {
        const f16* hin  = (t & 1) ? h1 : h0;
        f16*       hout = (t & 1) ? h0 : h1;

        // prefetch own cell values (written by this same thread last step)
        float cv0[4], cv1[4];
#pragma unroll
        for (int r = 0; r < 4; ++r) {
            cv0[r] = cglob[gbase + r * NH];
            cv1[r] = cglob[gbase + (16 + r) * NH];
        }

        const f16* a0p = hin + aoff0;
        const f16* a1p = hin + aoff1;

        f16x8 a0[4], a1[4];
#pragma unroll
        for (int s = 0; s < 4; ++s) {
            a0[s] = *(const f16x8*)(a0p + s * 32);
            a1[s] = *(const f16x8*)(a1p + s * 32);
        }
        f16x8 b0 = lb[(0 * 32 + 0) * 64 + lane];
        f16x8 b1 = lb[(1 * 32 + 0) * 64 + lane];
        f16x8 b2 = lb[(2 * 32 + 0) * 64 + lane];
        f16x8 b3 = lb[(3 * 32 + 0) * 64 + lane];

        f32x4 acc[2][4];
#pragma unroll
        for (int i = 0; i < 2; ++i)
#pragma unroll
            for (int g = 0; g < 4; ++g) acc[i][g] = f32x4{0.f, 0.f, 0.f, 0.f};

#pragma unroll
        for (int kb = 0; kb < 32; ++kb) {
            const int kn = (kb + 1) & 31;                   // kb=31 reads frag 0 (discarded)
            f16x8 n0 = lb[(0 * 32 + kn) * 64 + lane];
            f16x8 n1 = lb[(1 * 32 + kn) * 64 + lane];
            f16x8 n2 = lb[(2 * 32 + kn) * 64 + lane];
            f16x8 n3 = lb[(3 * 32 + kn) * 64 + lane];
            const f16x8 fa0 = a0[kb & 3], fa1 = a1[kb & 3];
            if (kb + 4 < 32) {
                a0[kb & 3] = *(const f16x8*)(a0p + (kb + 4) * 32);
                a1[kb & 3] = *(const f16x8*)(a1p + (kb + 4) * 32);
            }
            acc[0][0] = __builtin_amdgcn_mfma_f32_16x16x32_f16(fa0, b0, acc[0][0], 0, 0, 0);
            acc[0][1] = __builtin_amdgcn_mfma_f32_16x16x32_f16(fa0, b1, acc[0][1], 0, 0, 0);
            acc[0][2] = __builtin_amdgcn_mfma_f32_16x16x32_f16(fa0, b2, acc[0][2], 0, 0, 0);
            acc[0][3] = __builtin_amdgcn_mfma_f32_16x16x32_f16(fa0, b3, acc[0][3], 0, 0, 0);
            acc[1][0] = __builtin_amdgcn_mfma_f32_16x16x32_f16(fa1, b0, acc[1][0], 0, 0, 0);
            acc[1][1] = __builtin_amdgcn_mfma_f32_16x16x32_f16(fa1, b1, acc[1][1], 0, 0, 0);
            acc[1][2] = __builtin_amdgcn_mfma_f32_16x16x32_f16(fa1, b2, acc[1][2], 0, 0, 0);
            acc[1][3] = __builtin_amdgcn_mfma_f32_16x16x32_f16(fa1, b3, acc[1][3], 0, 0, 0);
            b0 = n0; b1 = n1; b2 = n2; b3 = n3;
        }

        // elementwise (all 4 gates lane-local) + h/c write + out-column partial
#pragma unroll
        for (int i = 0; i < 2; ++i) {
#pragma unroll
            for (int r = 0; r < 4; ++r) {
                const int gi = gbase + (i * 16 + r) * NH;
                const float iv = acc[i][0][r] + bi;
                const float fv = acc[i][1][r] + bf;
                const float gv = acc[i][2][r] + bg;
                const float ov = acc[i][3][r] + bo;
                const float cprev = i ? cv1[r] : cv0[r];
                const float cn = sigm(fv) * cprev + sigm(iv) * tanhf_(gv);
                cglob[gi] = cn;
                const float hv = sigm(ov) * tanhf_(cn);
                hout[gi] = (f16)hv;
                float pd = hv * wfc_u;                      // partial over this 16-unit strip
                pd += __shfl_xor(pd, 1);
                pd += __shfl_xor(pd, 2);
                pd += __shfl_xor(pd, 4);
                pd += __shfl_xor(pd, 8);
                if (l16 == 0)
                    atomicAdd(out + (rows0 + i * 16 + quad * 4 + r) * NSEQ + t, pd);
            }
        }

        if (t + 1 < NSEQ) {
            // ---- manual grid barrier: all 256 blocks completed step t ----
            __syncthreads();                       // block's writes issued
            if (tid == 0) {
                __threadfence();                   // agent-scope release (L2 writeback)
                atomicAdd(bar, 1u);
                const unsigned target = (unsigned)t * 256u;
                if (!dead) {
                    unsigned tries = 0;
                    while (__hip_atomic_load(bar, __ATOMIC_RELAXED,
                                             __HIP_MEMORY_SCOPE_AGENT) < target) {
                        if (++tries > 2000000u) { dead = 1; break; }  // fail fast, no hang
                    }
                }
                __threadfence();                   // agent-scope acquire (L1 invalidate)
            }
            __syncthreads();                       // propagate to whole block
        }
    }
}

extern "C" void kernel_launch(void* const* d_in, const int* in_sizes, int n_in,
                              void* d_out, int out_size, void* d_ws, size_t ws_size,
                              hipStream_t stream) {
    const float* xt     = (const float*)d_in[0];
    const float* hidden = (const float*)d_in[1];
    float*       cglob  = (float*)d_in[2];     // cell state updated IN PLACE (restored each launch)
    const float* W_ih   = (const float*)d_in[3];
    const float* W_hh   = (const float*)d_in[4];
    const float* b_ih   = (const float*)d_in[5];
    const float* b_hh   = (const float*)d_in[6];
    const float* W_fc   = (const float*)d_in[7];
    const float* b_fc   = (const float*)d_in[8];
    float* out = (float*)d_out;
    const float* wfc_last = W_fc + 127 * NH;   // row 127 of W_fc, f32

    // 11,681,796 B total — under the R1-proven 11,943,936 budget.
    char* ws = (char*)d_ws;
    f16*   weff     = (f16*)(ws);               // 4096*1024*2 = 8,388,608
    f16*   wih      = (f16*)(ws + 8388608);     // 4096*128*2  = 1,048,576
    f16*   xbuf     = (f16*)(ws + 9437184);     // 512*128*2   =   131,072
    f16*   h0       = (f16*)(ws + 9568256);     // 512*1024*2  = 1,048,576
    f16*   h1       = (f16*)(ws + 10616832);    // 512*1024*2  = 1,048,576
    float* bias_eff = (float*)(ws + 11665408);  // 4096*4      =    16,384
    unsigned* bar   = (unsigned*)(ws + 11681792); // 4 B grid-barrier counter

    hipLaunchKernelGGL(prep1_kernel, dim3(256), dim3(256), 0, stream,
                       xt, hidden, W_ih, b_ih, b_hh, b_fc, wih, xbuf, h0, bias_eff, out, bar);
    hipLaunchKernelGGL(prep2_kernel, dim3(512), dim3(256), 0, stream,
                       wih, W_fc, W_hh, weff);
    hipLaunchKernelGGL(step0_kernel, dim3(256), dim3(256), 0, stream,
                       xbuf, h0, h1, wih, W_hh, b_ih, b_hh, cglob);
    // out col 0 <- h_1
    hipLaunchKernelGGL(colget_kernel, dim3(8), dim3(256), 0, stream,
                       h1, wfc_last, b_fc, out, 0);

    // steps t=1..95 in one persistent kernel (cols 1..95 via atomics)
    hipLaunchKernelGGL(lstm_persist, dim3(256), dim3(256), 0, stream,
                       h0, h1, weff, bias_eff, cglob, wfc_last, out, bar);
}